// Round 17
// baseline (217.297 us; speedup 1.0000x reference)
//
#include <hip/hip_runtime.h>
#include <hip/hip_bf16.h>
#include <math.h>

#define EMBED 1024
#define HEADS 16
#define DH    64
#define BATCH 2
#define SEQ   2048

typedef __attribute__((ext_vector_type(8))) short bf16x8;
typedef __attribute__((ext_vector_type(4))) short bf16x4;
typedef __attribute__((ext_vector_type(4))) float f32x4;
typedef unsigned long long u64;
typedef __attribute__((ext_vector_type(2))) unsigned long long u64x2;

#define QSCALE 0.1803368801111244f   // 0.125 * log2(e): exp(s/8) == exp2(s*QSCALE)

static __device__ __forceinline__ unsigned short f2bf(float x) {
    unsigned u = __builtin_bit_cast(unsigned, x);
    return (unsigned short)((u + 0x7fffu + ((u >> 16) & 1u)) >> 16);
}
static __device__ __forceinline__ unsigned pk2bf(float a, float b) {
    union { __hip_bfloat162 h2; unsigned u; } c;
    c.h2 = __float22bfloat162_rn(make_float2(a, b));
    return c.u;
}
// raw hardware exp2 (single v_exp_f32; skips libm guard sequence)
static __device__ __forceinline__ float fexp2(float x) {
#if __has_builtin(__builtin_amdgcn_exp2f)
    return __builtin_amdgcn_exp2f(x);
#else
    float r; asm("v_exp_f32 %0, %1" : "=v"(r) : "v"(x)); return r;
#endif
}
// async global->LDS DMA, 16 B per lane; LDS dest = wave-uniform base + lane*16
static __device__ __forceinline__ void gl_lds16(const void* g, void* l) {
    __builtin_amdgcn_global_load_lds(
        (const __attribute__((address_space(1))) void*)g,
        (__attribute__((address_space(3))) void*)l, 16, 0, 0);
}
// convert 16 consecutive fp32 (two float4 pairs) to one bf16x8 fragment
static __device__ __forceinline__ bf16x8 cvt8(const float* p) {
    float4 a = ((const float4*)p)[0];
    float4 b = ((const float4*)p)[1];
    union { unsigned u[4]; bf16x8 v; } c;
    c.u[0] = pk2bf(a.x, a.y); c.u[1] = pk2bf(a.z, a.w);
    c.u[2] = pk2bf(b.x, b.y); c.u[3] = pk2bf(b.z, b.w);
    return c.v;
}

// ---------------------------------------------------------------------------
// Kernel 1 (R16 mega-proj, frozen): grid = (1024, 4), block = 256.
//   which 0/1: Q/K projection via SWAPPED MFMA C = W·X^T; packed 8B stores.
//   which 2  : V projection TRANSPOSED, C = W·X^T -> vt[bh][d][perm(s)]
//              (key permutation makes attn's K=32 PV B-frag contiguous).
//   which 3  : blk<512 maskpack | blk>=512 Wo fp32->bf16.
// ---------------------------------------------------------------------------
__global__ __launch_bounds__(256) void proj_mfma(
    const float* __restrict__ q, const float* __restrict__ k, const float* __restrict__ v,
    const float* __restrict__ Wq, const float* __restrict__ bq,
    const float* __restrict__ Wk, const float* __restrict__ bk,
    const float* __restrict__ Wv, const float* __restrict__ bv,
    unsigned short* __restrict__ qh, unsigned short* __restrict__ kh,
    unsigned short* __restrict__ vt,
    const int* __restrict__ mask, u64* __restrict__ bits,
    const float* __restrict__ Wo, unsigned short* __restrict__ Wob)
{
    const int blk   = blockIdx.x;
    const int which = blockIdx.y;
    const int t     = threadIdx.x;

    if (which == 3) {                     // ---- prep jobs (no LDS, no barrier) ----
        if (blk < 512) {                  // mask -> bitmask
            const int idx = blk * 256 + t;
            const int4* src = (const int4*)(mask + (size_t)idx * 64);
            u64 wb = 0;
#pragma unroll
            for (int u = 0; u < 16; ++u) {
                int4 m = src[u];
                u64 nib = (m.x != 0 ? 1ull : 0) | (m.y != 0 ? 2ull : 0) |
                          (m.z != 0 ? 4ull : 0) | (m.w != 0 ? 8ull : 0);
                wb |= nib << (u * 4);
            }
            bits[idx] = wb;
        } else {                          // Wo fp32 -> bf16
            const int i = ((blk - 512) * 256 + t) * 8;
            float4 a = ((const float4*)(Wo + i))[0];
            float4 b = ((const float4*)(Wo + i))[1];
            unsigned o32[4] = {pk2bf(a.x, a.y), pk2bf(a.z, a.w),
                               pk2bf(b.x, b.y), pk2bf(b.z, b.w)};
            *(uint4*)(Wob + i) = *(uint4*)o32;
        }
        return;
    }

    const float* x; const float* W; const float* bias;
    if (which == 0)      { x = q; W = Wq; bias = bq; }
    else if (which == 1) { x = k; W = Wk; bias = bk; }
    else                 { x = v; W = Wv; bias = bv; }

    __shared__ unsigned short Ws[64 * 72];

    const int w    = t >> 6;
    const int lane = t & 63;
    const int l15  = lane & 15;
    const int quad = lane >> 4;

    // ---- stage W into LDS (cooperative, one pass; verified R2 layout) ----
    const int sr = t >> 2, sp = t & 3;
    {
        const float* wsrc = W + (size_t)sr * 64 + sp * 16;
        unsigned o32[8];
#pragma unroll
        for (int u4 = 0; u4 < 4; ++u4) {
            float4 a = ((const float4*)wsrc)[u4];
            o32[u4 * 2 + 0] = pk2bf(a.x, a.y);
            o32[u4 * 2 + 1] = pk2bf(a.z, a.w);
        }
        *(uint4*)&Ws[sr * 72 + sp * 16]     = *(uint4*)&o32[0];
        *(uint4*)&Ws[sr * 72 + sp * 16 + 8] = *(uint4*)&o32[4];
    }

    if (which == 2) {                     // ---- V: C = W·X^T -> vt (key-permuted) ----
        const int bh = blk >> 5;          // (b,h) 0..31
        const int st = blk & 31;          // s-tile
        const int b  = bh >> 4, h = bh & 15;
        const int c  = w * 16 + l15;      // in-tile key 0..63
        const int s  = st * 64 + c;
        // storage position for key c: 32sp + 8q + 4h16 + m
        const int cp = (c & 32) + ((c & 12) << 1) + ((c & 16) >> 2) + (c & 3);

        const float* xrow = x + ((size_t)(b * SEQ + s)) * EMBED + h * DH;
        const bf16x8 bx0 = cvt8(xrow + quad * 8);
        const bf16x8 bx1 = cvt8(xrow + 32 + quad * 8);

        __syncthreads();

#pragma unroll
        for (int nt = 0; nt < 4; ++nt) {
            bf16x8 aw0 = *(const bf16x8*)&Ws[(nt * 16 + l15) * 72 + quad * 8];
            bf16x8 aw1 = *(const bf16x8*)&Ws[(nt * 16 + l15) * 72 + 32 + quad * 8];
            f32x4 a = {0, 0, 0, 0};
            a = __builtin_amdgcn_mfma_f32_16x16x32_bf16(aw0, bx0, a, 0, 0, 0);
            a = __builtin_amdgcn_mfma_f32_16x16x32_bf16(aw1, bx1, a, 0, 0, 0);
#pragma unroll
            for (int r = 0; r < 4; ++r) {
                const int d = nt * 16 + quad * 4 + r;
                vt[((size_t)bh * DH + d) * SEQ + st * 64 + cp] = f2bf(a[r] + bias[d]);
            }
        }
        return;
    }

    // ---- Q/K: SWAPPED C = W·X^T; packed 8B stores ----
    const float oscale = (which == 0) ? QSCALE : 1.0f;
    unsigned short* out = (which == 0) ? qh : kh;

    const float* xrow = x + ((size_t)blk * 64 + w * 16 + l15) * 64;
    const bf16x8 bx0 = cvt8(xrow + quad * 8);
    const bf16x8 bx1 = cvt8(xrow + 32 + quad * 8);

    __syncthreads();

    const int bs = blk * 4 + w;
    const int b = bs >> 11, s = bs & 2047;
    unsigned short* obase = out + (((size_t)b * HEADS + l15) * SEQ + s) * DH + quad * 4;

#pragma unroll
    for (int nt = 0; nt < 4; ++nt) {
        bf16x8 aw0 = *(const bf16x8*)&Ws[(nt * 16 + l15) * 72 + quad * 8];
        bf16x8 aw1 = *(const bf16x8*)&Ws[(nt * 16 + l15) * 72 + 32 + quad * 8];
        f32x4 a = {0, 0, 0, 0};
        a = __builtin_amdgcn_mfma_f32_16x16x32_bf16(aw0, bx0, a, 0, 0, 0);
        a = __builtin_amdgcn_mfma_f32_16x16x32_bf16(aw1, bx1, a, 0, 0, 0);
        const int d0 = nt * 16 + quad * 4;
        const float4 bb = *(const float4*)&bias[d0];
        unsigned o2[2] = {pk2bf((a[0] + bb.x) * oscale, (a[1] + bb.y) * oscale),
                          pk2bf((a[2] + bb.z) * oscale, (a[3] + bb.w) * oscale)};
        *(uint2*)(obase + nt * 16) = *(uint2*)o2;
    }
}

// ---------------------------------------------------------------------------
// Kernel 2 (R17): MFMA flash attention — 4x occupancy version.
// R16's instruction mix (K=32 packed PV, permuted-V b128, conflict-free;
// raw exp2; counted vmem) reshaped to 64-q-row blocks (4 waves x 16 rows),
// K-step 64, LDS 2 x 16KB = 32KB -> 4 blocks/CU = 4 waves/SIMD (was 2).
// R16 counters showed latency-bound (Mfma 26 + VALU 48, HBM 5%, conflicts
// 0, occupancy 17.9): doubling resident waves halves exposed dependency
// stall. Work totals (MFMA/VALU/LDS bytes) unchanged vs R16.
// Per-it vmem group: 4 gl_lds + 1 mask load = 5; pm-copy drains post-
// compute (cheap, R12/R16-verified behavior).
// grid = flat 1024; bh = bid & 31.
// ---------------------------------------------------------------------------
__global__ __launch_bounds__(256, 4) void attn_kernel(
    const unsigned short* __restrict__ qh, const unsigned short* __restrict__ kh,
    const unsigned short* __restrict__ vt, const u64* __restrict__ mbits,
    unsigned short* __restrict__ ctx)
{
    const int bid = blockIdx.x;
    const int bh  = bid & 31;
    const int q0  = (bid >> 5) * 64;      // 64-row Q panel
    const int b   = bh >> 4;

    __shared__ unsigned char smem[32768];   // buf(16K) x2: [K 8K | V 8K]

    const int t    = threadIdx.x;
    const int w    = t >> 6;              // wave id 0..3: 16 q-rows each
    const int lane = t & 63;
    const int l15  = lane & 15;
    const int quad = lane >> 4;

    const int srow   = lane >> 3;
    const int schunk = (lane & 7) ^ srow;

    // Q fragments (16 rows per wave, resident for the whole loop)
    const unsigned short* qb = qh + ((size_t)bh * SEQ + q0 + w * 16 + l15) * DH + quad * 8;
    const bf16x8 qf0 = *(const bf16x8*)qb;
    const bf16x8 qf1 = *(const bf16x8*)(qb + 32);

    f32x4 O[4];
#pragma unroll
    for (int dt = 0; dt < 4; ++dt) O[dt] = f32x4{0, 0, 0, 0};
    f32x4 Osum = {0, 0, 0, 0};
    const bf16x8 ones8 = {(short)0x3F80, (short)0x3F80, (short)0x3F80, (short)0x3F80,
                          (short)0x3F80, (short)0x3F80, (short)0x3F80, (short)0x3F80};

    const unsigned short* kbase = kh + (size_t)bh * SEQ * DH
                                  + (size_t)srow * DH + schunk * 8;
    const unsigned short* vbase = vt + (size_t)bh * DH * SEQ
                                  + (size_t)srow * SEQ + schunk * 8;
    const u64* mrow = mbits + ((size_t)b * SEQ + q0 + w * 16 + l15) * (SEQ / 64);

    // stage 64-key tile kt into buf: 16 x 1KB issues over 4 waves (4/wave).
    auto stage = [&](int kt, unsigned char* buf) {
#pragma unroll
        for (int j = 0; j < 4; ++j) {
            const int idx = w * 4 + j;
            if (idx < 8)
                gl_lds16(kbase + ((size_t)kt * 64 + idx * 8) * DH, buf + idx * 1024);
            else
                gl_lds16(vbase + kt * 64 + (size_t)(idx - 8) * 8 * SEQ,
                         buf + 8192 + (idx - 8) * 1024);
        }
    };

    stage(0, smem);
    u64 pm = mrow[0];
    __syncthreads();                      // prologue: full drain

    for (int it = 0; it < 32; ++it) {
        u64 nM = 0;
        if (it < 31) {
            // issue group: 4 gl_lds + 1 mask vector-load = 5 vmem ops
            stage(it + 1, smem + ((it + 1) & 1) * 16384);
            nM = mrow[it + 1];
            asm volatile("s_waitcnt vmcnt(5)" ::: "memory");
        } else {
            asm volatile("s_waitcnt vmcnt(0)" ::: "memory");
        }
        __builtin_amdgcn_s_barrier();     // all waves' buf(it) DMAs complete
        __builtin_amdgcn_sched_barrier(0);

        const unsigned char* buf = smem + (it & 1) * 16384;
        const unsigned short* KtH = (const unsigned short*)buf;
        const unsigned short* VtH = (const unsigned short*)(buf + 8192);
        const u64 mq = pm >> (quad * 4);

        __builtin_amdgcn_s_setprio(1);

        // ---- S^T subtiles + masked exp2; P packed to bf16x8 (K=32) ----
        unsigned pw[2][4];                // [sp][word]
        const int rx = l15 & 7;
#pragma unroll
        for (int st = 0; st < 4; ++st) {
            const int r = st * 16 + l15;
            bf16x8 kf0 = *(const bf16x8*)&KtH[r * 64 + ((quad ^ rx)) * 8];
            bf16x8 kf1 = *(const bf16x8*)&KtH[r * 64 + ((quad ^ rx) ^ 4) * 8];
            f32x4 sa = {0, 0, 0, 0};
            sa = __builtin_amdgcn_mfma_f32_16x16x32_bf16(kf0, qf0, sa, 0, 0, 0);
            sa = __builtin_amdgcn_mfma_f32_16x16x32_bf16(kf1, qf1, sa, 0, 0, 0);
            const unsigned nib = (unsigned)(mq >> (st * 16)) & 0xFu;
            float p0 = (nib & 1u) ? fexp2(sa[0]) : 0.f;
            float p1 = (nib & 2u) ? fexp2(sa[1]) : 0.f;
            float p2 = (nib & 4u) ? fexp2(sa[2]) : 0.f;
            float p3 = (nib & 8u) ? fexp2(sa[3]) : 0.f;
            pw[st >> 1][2 * (st & 1)]     = pk2bf(p0, p1);
            pw[st >> 1][2 * (st & 1) + 1] = pk2bf(p2, p3);
        }
        bf16x8 p8[2];
#pragma unroll
        for (int sp = 0; sp < 2; ++sp) {
            union { unsigned u4[4]; bf16x8 v; } pu;
            pu.u4[0] = pw[sp][0]; pu.u4[1] = pw[sp][1];
            pu.u4[2] = pw[sp][2]; pu.u4[3] = pw[sp][3];
            p8[sp] = pu.v;
            Osum = __builtin_amdgcn_mfma_f32_16x16x32_bf16(p8[sp], ones8, Osum, 0, 0, 0);
        }

        // ---- PV (K=32): O[dt] += P8 * V (b128 reads, conflict-free) ----
#pragma unroll
        for (int dt = 0; dt < 4; ++dt) {
            const int d = dt * 16 + l15;
            const int dx = l15 & 7;
#pragma unroll
            for (int sp = 0; sp < 2; ++sp) {
                const int ch = (sp * 4 + quad) ^ dx;
                bf16x8 vb = *(const bf16x8*)&VtH[d * 64 + ch * 8];
                O[dt] = __builtin_amdgcn_mfma_f32_16x16x32_bf16(p8[sp], vb, O[dt], 0, 0, 0);
            }
        }
        __builtin_amdgcn_s_setprio(0);
        __builtin_amdgcn_sched_barrier(0);
        __builtin_amdgcn_s_barrier();     // all waves done reading buf(it)

        if (it < 31) pm = nM;             // post-compute drain (cheap)
    }

    // ---- epilogue: direct store, wave-local denominator ----
    float inv[4];
#pragma unroll
    for (int r = 0; r < 4; ++r) inv[r] = 1.0f / Osum[r];
#pragma unroll
    for (int r = 0; r < 4; ++r) {
        const int row = q0 + w * 16 + quad * 4 + r;
        unsigned short* dst = ctx + ((size_t)bh * SEQ + row) * DH + l15;
#pragma unroll
        for (int dt = 0; dt < 4; ++dt)
            dst[dt * 16] = f2bf(O[dt][r] * inv[r]);
    }
}

// ---------------------------------------------------------------------------
// Kernel 3 (R11, frozen): output projection — 128x64 C-tile, BK = 64.
// grid = (16, 32), block = 256.
// ---------------------------------------------------------------------------
__global__ __launch_bounds__(256, 3) void outproj_mfma(
    const unsigned short* __restrict__ ctx, const unsigned short* __restrict__ Wob,
    const float* __restrict__ bo, float* __restrict__ out)
{
    const int n0 = blockIdx.x * 64;
    const int m0 = blockIdx.y * 128;
    const int b  = m0 / SEQ;
    const int s0 = m0 % SEQ;

    __shared__ unsigned char smem[49152];   // buf(24K) x2: [A 16K | W 8K]

    const int t    = threadIdx.x;
    const int w    = t >> 6;
    const int lane = t & 63;
    const int l15  = lane & 15;
    const int quad = lane >> 4;
    const int srow   = lane >> 3;
    const int schunk = (lane & 7) ^ srow;

    const unsigned short* abase = ctx + ((size_t)b * HEADS * SEQ + s0 + srow) * DH + schunk * 8;
    const unsigned short* wbase = Wob + (size_t)(n0 + srow) * EMBED + schunk * 8;

    f32x4 acc[8];
#pragma unroll
    for (int mt = 0; mt < 8; ++mt) acc[mt] = f32x4{0, 0, 0, 0};

    auto stage = [&](int kt, unsigned char* buf) {
#pragma unroll
        for (int j = 0; j < 6; ++j) {
            const int idx = w * 6 + j;
            if (idx < 16)
                gl_lds16(abase + (size_t)kt * SEQ * DH + (size_t)idx * 8 * DH,
                         buf + idx * 1024);
            else
                gl_lds16(wbase + (size_t)(idx - 16) * 8 * EMBED + kt * 64,
                         buf + 16384 + (idx - 16) * 1024);
        }
    };

    stage(0, smem);
    __syncthreads();

    for (int kt = 0; kt < 16; ++kt) {
        if (kt < 15) stage(kt + 1, smem + ((kt + 1) & 1) * 24576);

        const unsigned char* buf = smem + (kt & 1) * 24576;
        const unsigned short* At = (const unsigned short*)buf;
        const unsigned short* Wt = (const unsigned short*)(buf + 16384);
        const int rx = l15 & 7;
        const int c0 = ((quad ^ rx)) * 8;

        __builtin_amdgcn_s_setprio(1);
        bf16x8 bf0 = *(const bf16x8*)&Wt[(w * 16 + l15) * 64 + c0];
        bf16x8 bf1 = *(const bf16x8*)&Wt[(w * 16 + l15) * 64 + (c0 ^ 32)];
#pragma unroll
        for (int mt = 0; mt < 8; ++mt) {
            bf16x8 af0 = *(const bf16x8*)&At[(mt * 16 + l15) * 64 + c0];
            bf16x8 af1 = *(const bf16x8*)&At[(mt * 16 + l15) * 64 + (c0 ^ 32)];
            acc[mt] = __builtin_amdgcn_mfma_f32_16x16x32_bf16(af0, bf0, acc[mt], 0, 0, 0);
            acc[mt] = __builtin_amdgcn_mfma_f32_16x16x32_bf16(af1, bf1, acc[mt], 0, 0, 0);
        }
        __builtin_amdgcn_s_setprio(0);
        __syncthreads();
    }

    const float bv = bo[n0 + w * 16 + l15];
#pragma unroll
    for (int mt = 0; mt < 8; ++mt) {
#pragma unroll
        for (int r = 0; r < 4; ++r) {
            out[(size_t)(m0 + mt * 16 + quad * 4 + r) * EMBED + n0 + w * 16 + l15] =
                acc[mt][r] + bv;
        }
    }
}

// ---------------------------------------------------------------------------
extern "C" void kernel_launch(void* const* d_in, const int* in_sizes, int n_in,
                              void* d_out, int out_size, void* d_ws, size_t ws_size,
                              hipStream_t stream) {
    const float* k    = (const float*)d_in[0];
    const float* q    = (const float*)d_in[1];
    const float* v    = (const float*)d_in[2];
    const int*   mask = (const int*)  d_in[3];
    const float* Wk   = (const float*)d_in[4];
    const float* bk   = (const float*)d_in[5];
    const float* Wq   = (const float*)d_in[6];
    const float* bq   = (const float*)d_in[7];
    const float* Wv   = (const float*)d_in[8];
    const float* bv   = (const float*)d_in[9];
    const float* Wo   = (const float*)d_in[10];
    const float* bo   = (const float*)d_in[11];
    float* out = (float*)d_out;

    const size_t TEN = (size_t)BATCH * HEADS * SEQ * DH;   // 4,194,304 elems
    unsigned short* qh_bf = (unsigned short*)d_ws;         // 8 MB
    unsigned short* kh_bf = qh_bf + TEN;                   // 8 MB
    unsigned short* vt_bf = kh_bf + TEN;                   // 8 MB
    unsigned short* ctxb  = vt_bf + TEN;                   // 8 MB
    unsigned short* Wob   = ctxb + TEN;                    // 2 MB
    u64*            mbits = (u64*)(Wob + EMBED * EMBED);   // 1 MB  (35 MB total)

    proj_mfma<<<dim3(1024, 4), 256, 0, stream>>>(
        q, k, v, Wq, bq, Wk, bk, Wv, bv,
        qh_bf, kh_bf, vt_bf, mask, mbits, Wo, Wob);
    attn_kernel<<<dim3((SEQ / 64) * BATCH * HEADS), 256, 0, stream>>>(
        qh_bf, kh_bf, vt_bf, mbits, ctxb);
    outproj_mfma<<<dim3(EMBED / 64, BATCH * SEQ / 128), 256, 0, stream>>>(
        ctxb, Wob, bo, out);
}

// Round 18
// 209.275 us; speedup vs baseline: 1.0383x; 1.0383x over previous
//
#include <hip/hip_runtime.h>
#include <hip/hip_bf16.h>
#include <math.h>

#define EMBED 1024
#define HEADS 16
#define DH    64
#define BATCH 2
#define SEQ   2048

typedef __attribute__((ext_vector_type(8))) short bf16x8;
typedef __attribute__((ext_vector_type(4))) short bf16x4;
typedef __attribute__((ext_vector_type(4))) float f32x4;
typedef unsigned long long u64;
typedef __attribute__((ext_vector_type(2))) unsigned long long u64x2;

#define QSCALE 0.1803368801111244f   // 0.125 * log2(e): exp(s/8) == exp2(s*QSCALE)

static __device__ __forceinline__ unsigned short f2bf(float x) {
    unsigned u = __builtin_bit_cast(unsigned, x);
    return (unsigned short)((u + 0x7fffu + ((u >> 16) & 1u)) >> 16);
}
static __device__ __forceinline__ unsigned pk2bf(float a, float b) {
    union { __hip_bfloat162 h2; unsigned u; } c;
    c.h2 = __float22bfloat162_rn(make_float2(a, b));
    return c.u;
}
// raw hardware exp2 (single v_exp_f32; skips libm guard sequence)
static __device__ __forceinline__ float fexp2(float x) {
#if __has_builtin(__builtin_amdgcn_exp2f)
    return __builtin_amdgcn_exp2f(x);
#else
    float r; asm("v_exp_f32 %0, %1" : "=v"(r) : "v"(x)); return r;
#endif
}
// async global->LDS DMA, 16 B per lane; LDS dest = wave-uniform base + lane*16
static __device__ __forceinline__ void gl_lds16(const void* g, void* l) {
    __builtin_amdgcn_global_load_lds(
        (const __attribute__((address_space(1))) void*)g,
        (__attribute__((address_space(3))) void*)l, 16, 0, 0);
}
// convert 16 consecutive fp32 (two float4 pairs) to one bf16x8 fragment
static __device__ __forceinline__ bf16x8 cvt8(const float* p) {
    float4 a = ((const float4*)p)[0];
    float4 b = ((const float4*)p)[1];
    union { unsigned u[4]; bf16x8 v; } c;
    c.u[0] = pk2bf(a.x, a.y); c.u[1] = pk2bf(a.z, a.w);
    c.u[2] = pk2bf(b.x, b.y); c.u[3] = pk2bf(b.z, b.w);
    return c.v;
}

// ---------------------------------------------------------------------------
// Kernel 1 (R16 mega-proj): grid = (1024, 4), block = 256.
//   which 0/1: Q/K projection via SWAPPED MFMA C = W·X^T; packed 8B stores.
//   which 2  : V projection TRANSPOSED, C = W·X^T -> vt[bh][d][perm(s)].
//              Key PERMUTATION within each 64-key tile: storage position
//              32sp+8q+4h+m holds key 32sp+16h+4q+m, so attn's PV B-frag
//              (mfma 16x16x32: k = quad*8+j) is 8 CONSECUTIVE ushorts.
//   which 3  : blk<512 maskpack | blk>=512 Wo fp32->bf16.
// ---------------------------------------------------------------------------
__global__ __launch_bounds__(256) void proj_mfma(
    const float* __restrict__ q, const float* __restrict__ k, const float* __restrict__ v,
    const float* __restrict__ Wq, const float* __restrict__ bq,
    const float* __restrict__ Wk, const float* __restrict__ bk,
    const float* __restrict__ Wv, const float* __restrict__ bv,
    unsigned short* __restrict__ qh, unsigned short* __restrict__ kh,
    unsigned short* __restrict__ vt,
    const int* __restrict__ mask, u64* __restrict__ bits,
    const float* __restrict__ Wo, unsigned short* __restrict__ Wob)
{
    const int blk   = blockIdx.x;
    const int which = blockIdx.y;
    const int t     = threadIdx.x;

    if (which == 3) {                     // ---- prep jobs (no LDS, no barrier) ----
        if (blk < 512) {                  // mask -> bitmask
            const int idx = blk * 256 + t;
            const int4* src = (const int4*)(mask + (size_t)idx * 64);
            u64 wb = 0;
#pragma unroll
            for (int u = 0; u < 16; ++u) {
                int4 m = src[u];
                u64 nib = (m.x != 0 ? 1ull : 0) | (m.y != 0 ? 2ull : 0) |
                          (m.z != 0 ? 4ull : 0) | (m.w != 0 ? 8ull : 0);
                wb |= nib << (u * 4);
            }
            bits[idx] = wb;
        } else {                          // Wo fp32 -> bf16
            const int i = ((blk - 512) * 256 + t) * 8;
            float4 a = ((const float4*)(Wo + i))[0];
            float4 b = ((const float4*)(Wo + i))[1];
            unsigned o32[4] = {pk2bf(a.x, a.y), pk2bf(a.z, a.w),
                               pk2bf(b.x, b.y), pk2bf(b.z, b.w)};
            *(uint4*)(Wob + i) = *(uint4*)o32;
        }
        return;
    }

    const float* x; const float* W; const float* bias;
    if (which == 0)      { x = q; W = Wq; bias = bq; }
    else if (which == 1) { x = k; W = Wk; bias = bk; }
    else                 { x = v; W = Wv; bias = bv; }

    __shared__ unsigned short Ws[64 * 72];

    const int w    = t >> 6;
    const int lane = t & 63;
    const int l15  = lane & 15;
    const int quad = lane >> 4;

    // ---- stage W into LDS (cooperative, one pass; verified R2 layout) ----
    const int sr = t >> 2, sp = t & 3;
    {
        const float* wsrc = W + (size_t)sr * 64 + sp * 16;
        unsigned o32[8];
#pragma unroll
        for (int u4 = 0; u4 < 4; ++u4) {
            float4 a = ((const float4*)wsrc)[u4];
            o32[u4 * 2 + 0] = pk2bf(a.x, a.y);
            o32[u4 * 2 + 1] = pk2bf(a.z, a.w);
        }
        *(uint4*)&Ws[sr * 72 + sp * 16]     = *(uint4*)&o32[0];
        *(uint4*)&Ws[sr * 72 + sp * 16 + 8] = *(uint4*)&o32[4];
    }

    if (which == 2) {                     // ---- V: C = W·X^T -> vt (key-permuted) ----
        const int bh = blk >> 5;          // (b,h) 0..31
        const int st = blk & 31;          // s-tile
        const int b  = bh >> 4, h = bh & 15;
        const int c  = w * 16 + l15;      // in-tile key 0..63
        const int s  = st * 64 + c;
        // storage position for key c: 32sp + 8q + 4h16 + m
        const int cp = (c & 32) + ((c & 12) << 1) + ((c & 16) >> 2) + (c & 3);

        const float* xrow = x + ((size_t)(b * SEQ + s)) * EMBED + h * DH;
        const bf16x8 bx0 = cvt8(xrow + quad * 8);
        const bf16x8 bx1 = cvt8(xrow + 32 + quad * 8);

        __syncthreads();

#pragma unroll
        for (int nt = 0; nt < 4; ++nt) {
            bf16x8 aw0 = *(const bf16x8*)&Ws[(nt * 16 + l15) * 72 + quad * 8];
            bf16x8 aw1 = *(const bf16x8*)&Ws[(nt * 16 + l15) * 72 + 32 + quad * 8];
            f32x4 a = {0, 0, 0, 0};
            a = __builtin_amdgcn_mfma_f32_16x16x32_bf16(aw0, bx0, a, 0, 0, 0);
            a = __builtin_amdgcn_mfma_f32_16x16x32_bf16(aw1, bx1, a, 0, 0, 0);
#pragma unroll
            for (int r = 0; r < 4; ++r) {
                const int d = nt * 16 + quad * 4 + r;
                vt[((size_t)bh * DH + d) * SEQ + st * 64 + cp] = f2bf(a[r] + bias[d]);
            }
        }
        return;
    }

    // ---- Q/K: SWAPPED C = W·X^T; packed 8B stores ----
    const float oscale = (which == 0) ? QSCALE : 1.0f;
    unsigned short* out = (which == 0) ? qh : kh;

    const float* xrow = x + ((size_t)blk * 64 + w * 16 + l15) * 64;
    const bf16x8 bx0 = cvt8(xrow + quad * 8);
    const bf16x8 bx1 = cvt8(xrow + 32 + quad * 8);

    __syncthreads();

    const int bs = blk * 4 + w;
    const int b = bs >> 11, s = bs & 2047;
    unsigned short* obase = out + (((size_t)b * HEADS + l15) * SEQ + s) * DH + quad * 4;

#pragma unroll
    for (int nt = 0; nt < 4; ++nt) {
        bf16x8 aw0 = *(const bf16x8*)&Ws[(nt * 16 + l15) * 72 + quad * 8];
        bf16x8 aw1 = *(const bf16x8*)&Ws[(nt * 16 + l15) * 72 + 32 + quad * 8];
        f32x4 a = {0, 0, 0, 0};
        a = __builtin_amdgcn_mfma_f32_16x16x32_bf16(aw0, bx0, a, 0, 0, 0);
        a = __builtin_amdgcn_mfma_f32_16x16x32_bf16(aw1, bx1, a, 0, 0, 0);
        const int d0 = nt * 16 + quad * 4;
        const float4 bb = *(const float4*)&bias[d0];
        unsigned o2[2] = {pk2bf((a[0] + bb.x) * oscale, (a[1] + bb.y) * oscale),
                          pk2bf((a[2] + bb.z) * oscale, (a[3] + bb.w) * oscale)};
        *(uint2*)(obase + nt * 16) = *(uint2*)o2;
    }
}

// ---------------------------------------------------------------------------
// Kernel 2 (R16, best measured — final): MFMA flash attention.
// R12 counted-vmcnt schedule + K=32 PV (P packed to bf16x8, permuted-V
// b128 reads, conflict-free). 212.0 us total / 57.9 us attn / conflicts 0.
// grid = flat 512; bh = bid & 31.
// ---------------------------------------------------------------------------
__global__ __launch_bounds__(256, 2) void attn_kernel(
    const unsigned short* __restrict__ qh, const unsigned short* __restrict__ kh,
    const unsigned short* __restrict__ vt, const u64* __restrict__ mbits,
    unsigned short* __restrict__ ctx)
{
    const int bid = blockIdx.x;
    const int bh  = bid & 31;
    const int q0  = (bid >> 5) * 128;     // 128-row Q panel
    const int b   = bh >> 4;

    __shared__ unsigned char smem[65536];   // buf(32K) x2: [K0 8K|K1 8K|V0 8K|V1 8K]

    const int t    = threadIdx.x;
    const int w    = t >> 6;              // wave id 0..3: 32 q-rows each
    const int lane = t & 63;
    const int l15  = lane & 15;
    const int quad = lane >> 4;

    const int srow   = lane >> 3;
    const int schunk = (lane & 7) ^ srow;

    // Q fragments: 2 subtiles of 16 rows per wave
    bf16x8 qf[2][2];
#pragma unroll
    for (int g = 0; g < 2; ++g) {
        const unsigned short* qb =
            qh + ((size_t)bh * SEQ + q0 + w * 32 + g * 16 + l15) * DH + quad * 8;
        qf[g][0] = *(const bf16x8*)qb;
        qf[g][1] = *(const bf16x8*)(qb + 32);
    }

    f32x4 O[2][4];
#pragma unroll
    for (int g = 0; g < 2; ++g)
#pragma unroll
        for (int dt = 0; dt < 4; ++dt) O[g][dt] = f32x4{0, 0, 0, 0};
    f32x4 Osum[2] = {f32x4{0, 0, 0, 0}, f32x4{0, 0, 0, 0}};
    const bf16x8 ones8 = {(short)0x3F80, (short)0x3F80, (short)0x3F80, (short)0x3F80,
                          (short)0x3F80, (short)0x3F80, (short)0x3F80, (short)0x3F80};

    const unsigned short* kbase = kh + (size_t)bh * SEQ * DH
                                  + (size_t)srow * DH + schunk * 8;
    const unsigned short* vbase = vt + (size_t)bh * DH * SEQ
                                  + (size_t)srow * SEQ + schunk * 8;
    const u64* mrow0 = mbits + ((size_t)b * SEQ + q0 + w * 32 + l15) * (SEQ / 64);
    const u64* mrow1 = mrow0 + 16 * (SEQ / 64);

    // stage key-pair kp into buf: 32 x 1KB issues over 4 waves (8/wave).
    auto stage = [&](int kp, unsigned char* buf) {
#pragma unroll
        for (int j = 0; j < 8; ++j) {
            const int idx = w * 8 + j;
            if (idx < 16) {
                const int u = idx >> 3, i = idx & 7;
                gl_lds16(kbase + ((size_t)kp * 128 + u * 64 + i * 8) * DH,
                         buf + u * 8192 + i * 1024);
            } else {
                const int u = (idx - 16) >> 3, i = (idx - 16) & 7;
                gl_lds16(vbase + kp * 128 + u * 64 + (size_t)i * 8 * SEQ,
                         buf + 16384 + u * 8192 + i * 1024);
            }
        }
    };

    stage(0, smem);
    u64 pm00 = mrow0[0], pm01 = mrow0[1], pm10 = mrow1[0], pm11 = mrow1[1];
    __syncthreads();                      // prologue: full drain, vmcnt = 0 at loop entry

    for (int it = 0; it < 16; ++it) {
        u64x2 nA, nB;
        if (it < 15) {
            // issue group: exactly 8 gl_lds + 2 vector mask loads = 10 vmem ops
            stage(it + 1, smem + ((it + 1) & 1) * 32768);
            nA = *(const u64x2*)&mrow0[2 * it + 2];   // 16B-aligned: one dwordx4
            nB = *(const u64x2*)&mrow1[2 * it + 2];
            // complete the PREVIOUS iteration's 10 (incl. buf(it) staging);
            // leave this iteration's 10 in flight across the barriers.
            asm volatile("s_waitcnt vmcnt(10)" ::: "memory");
        } else {
            asm volatile("s_waitcnt vmcnt(0)" ::: "memory");
        }
        __builtin_amdgcn_s_barrier();     // all waves' buf(it) DMAs complete
        __builtin_amdgcn_sched_barrier(0);

        const unsigned char* buf = smem + (it & 1) * 32768;

        __builtin_amdgcn_s_setprio(1);
#pragma unroll
        for (int u = 0; u < 2; ++u) {
            const unsigned short* KtH = (const unsigned short*)(buf + u * 8192);
            const unsigned short* VtH = (const unsigned short*)(buf + 16384 + u * 8192);
            const u64 mq0 = (u ? pm01 : pm00) >> (quad * 4);
            const u64 mq1 = (u ? pm11 : pm10) >> (quad * 4);

            // ---- S^T subtiles + masked exp2; P packed to bf16x8 (K=32) ----
            unsigned pw[2][2][4];         // [g][sp][word]
            const int rx = l15 & 7;
#pragma unroll
            for (int st = 0; st < 4; ++st) {
                const int r = st * 16 + l15;
                bf16x8 kf0 = *(const bf16x8*)&KtH[r * 64 + ((quad ^ rx)) * 8];
                bf16x8 kf1 = *(const bf16x8*)&KtH[r * 64 + ((quad ^ rx) ^ 4) * 8];
#pragma unroll
                for (int g = 0; g < 2; ++g) {
                    f32x4 sa = {0, 0, 0, 0};
                    sa = __builtin_amdgcn_mfma_f32_16x16x32_bf16(kf0, qf[g][0], sa, 0, 0, 0);
                    sa = __builtin_amdgcn_mfma_f32_16x16x32_bf16(kf1, qf[g][1], sa, 0, 0, 0);
                    const unsigned nib =
                        (unsigned)((g ? mq1 : mq0) >> (st * 16)) & 0xFu;
                    float p0 = (nib & 1u) ? fexp2(sa[0]) : 0.f;
                    float p1 = (nib & 2u) ? fexp2(sa[1]) : 0.f;
                    float p2 = (nib & 4u) ? fexp2(sa[2]) : 0.f;
                    float p3 = (nib & 8u) ? fexp2(sa[3]) : 0.f;
                    pw[g][st >> 1][2 * (st & 1)]     = pk2bf(p0, p1);
                    pw[g][st >> 1][2 * (st & 1) + 1] = pk2bf(p2, p3);
                }
            }
            // pack and row-sum (K=32 Osum: 2 MFMAs per g instead of 4)
            bf16x8 p8[2][2];
#pragma unroll
            for (int g = 0; g < 2; ++g)
#pragma unroll
                for (int sp = 0; sp < 2; ++sp) {
                    union { unsigned u4[4]; bf16x8 v; } pu;
                    pu.u4[0] = pw[g][sp][0]; pu.u4[1] = pw[g][sp][1];
                    pu.u4[2] = pw[g][sp][2]; pu.u4[3] = pw[g][sp][3];
                    p8[g][sp] = pu.v;
                    Osum[g] = __builtin_amdgcn_mfma_f32_16x16x32_bf16(
                        p8[g][sp], ones8, Osum[g], 0, 0, 0);
                }

            // ---- PV (K=32): O[g][dt] += P8 * V (b128 reads, K-style swizzle) ----
#pragma unroll
            for (int dt = 0; dt < 4; ++dt) {
                const int d = dt * 16 + l15;
                const int dx = l15 & 7;
#pragma unroll
                for (int sp = 0; sp < 2; ++sp) {
                    const int ch = (sp * 4 + quad) ^ dx;
                    bf16x8 vb = *(const bf16x8*)&VtH[d * 64 + ch * 8];
                    O[0][dt] = __builtin_amdgcn_mfma_f32_16x16x32_bf16(
                        p8[0][sp], vb, O[0][dt], 0, 0, 0);
                    O[1][dt] = __builtin_amdgcn_mfma_f32_16x16x32_bf16(
                        p8[1][sp], vb, O[1][dt], 0, 0, 0);
                }
            }
        }
        __builtin_amdgcn_s_setprio(0);
        __builtin_amdgcn_sched_barrier(0);
        __builtin_amdgcn_s_barrier();     // all waves done reading buf(it)

        if (it < 15) { pm00 = nA[0]; pm01 = nA[1]; pm10 = nB[0]; pm11 = nB[1]; }
    }

    // ---- epilogue: direct store, wave-local denominator ----
#pragma unroll
    for (int g = 0; g < 2; ++g) {
        float inv[4];
#pragma unroll
        for (int r = 0; r < 4; ++r) inv[r] = 1.0f / Osum[g][r];
#pragma unroll
        for (int r = 0; r < 4; ++r) {
            const int row = q0 + w * 32 + g * 16 + quad * 4 + r;
            unsigned short* dst = ctx + ((size_t)bh * SEQ + row) * DH + l15;
#pragma unroll
            for (int dt = 0; dt < 4; ++dt)
                dst[dt * 16] = f2bf(O[g][dt][r] * inv[r]);
        }
    }
}

// ---------------------------------------------------------------------------
// Kernel 3 (R11, frozen): output projection — 128x64 C-tile, BK = 64.
// grid = (16, 32), block = 256.
// ---------------------------------------------------------------------------
__global__ __launch_bounds__(256, 3) void outproj_mfma(
    const unsigned short* __restrict__ ctx, const unsigned short* __restrict__ Wob,
    const float* __restrict__ bo, float* __restrict__ out)
{
    const int n0 = blockIdx.x * 64;
    const int m0 = blockIdx.y * 128;
    const int b  = m0 / SEQ;
    const int s0 = m0 % SEQ;

    __shared__ unsigned char smem[49152];   // buf(24K) x2: [A 16K | W 8K]

    const int t    = threadIdx.x;
    const int w    = t >> 6;
    const int lane = t & 63;
    const int l15  = lane & 15;
    const int quad = lane >> 4;
    const int srow   = lane >> 3;
    const int schunk = (lane & 7) ^ srow;

    const unsigned short* abase = ctx + ((size_t)b * HEADS * SEQ + s0 + srow) * DH + schunk * 8;
    const unsigned short* wbase = Wob + (size_t)(n0 + srow) * EMBED + schunk * 8;

    f32x4 acc[8];
#pragma unroll
    for (int mt = 0; mt < 8; ++mt) acc[mt] = f32x4{0, 0, 0, 0};

    auto stage = [&](int kt, unsigned char* buf) {
#pragma unroll
        for (int j = 0; j < 6; ++j) {
            const int idx = w * 6 + j;
            if (idx < 16)
                gl_lds16(abase + (size_t)kt * SEQ * DH + (size_t)idx * 8 * DH,
                         buf + idx * 1024);
            else
                gl_lds16(wbase + (size_t)(idx - 16) * 8 * EMBED + kt * 64,
                         buf + 16384 + (idx - 16) * 1024);
        }
    };

    stage(0, smem);
    __syncthreads();

    for (int kt = 0; kt < 16; ++kt) {
        if (kt < 15) stage(kt + 1, smem + ((kt + 1) & 1) * 24576);

        const unsigned char* buf = smem + (kt & 1) * 24576;
        const unsigned short* At = (const unsigned short*)buf;
        const unsigned short* Wt = (const unsigned short*)(buf + 16384);
        const int rx = l15 & 7;
        const int c0 = ((quad ^ rx)) * 8;

        __builtin_amdgcn_s_setprio(1);
        bf16x8 bf0 = *(const bf16x8*)&Wt[(w * 16 + l15) * 64 + c0];
        bf16x8 bf1 = *(const bf16x8*)&Wt[(w * 16 + l15) * 64 + (c0 ^ 32)];
#pragma unroll
        for (int mt = 0; mt < 8; ++mt) {
            bf16x8 af0 = *(const bf16x8*)&At[(mt * 16 + l15) * 64 + c0];
            bf16x8 af1 = *(const bf16x8*)&At[(mt * 16 + l15) * 64 + (c0 ^ 32)];
            acc[mt] = __builtin_amdgcn_mfma_f32_16x16x32_bf16(af0, bf0, acc[mt], 0, 0, 0);
            acc[mt] = __builtin_amdgcn_mfma_f32_16x16x32_bf16(af1, bf1, acc[mt], 0, 0, 0);
        }
        __builtin_amdgcn_s_setprio(0);
        __syncthreads();
    }

    const float bv = bo[n0 + w * 16 + l15];
#pragma unroll
    for (int mt = 0; mt < 8; ++mt) {
#pragma unroll
        for (int r = 0; r < 4; ++r) {
            out[(size_t)(m0 + mt * 16 + quad * 4 + r) * EMBED + n0 + w * 16 + l15] =
                acc[mt][r] + bv;
        }
    }
}

// ---------------------------------------------------------------------------
extern "C" void kernel_launch(void* const* d_in, const int* in_sizes, int n_in,
                              void* d_out, int out_size, void* d_ws, size_t ws_size,
                              hipStream_t stream) {
    const float* k    = (const float*)d_in[0];
    const float* q    = (const float*)d_in[1];
    const float* v    = (const float*)d_in[2];
    const int*   mask = (const int*)  d_in[3];
    const float* Wk   = (const float*)d_in[4];
    const float* bk   = (const float*)d_in[5];
    const float* Wq   = (const float*)d_in[6];
    const float* bq   = (const float*)d_in[7];
    const float* Wv   = (const float*)d_in[8];
    const float* bv   = (const float*)d_in[9];
    const float* Wo   = (const float*)d_in[10];
    const float* bo   = (const float*)d_in[11];
    float* out = (float*)d_out;

    const size_t TEN = (size_t)BATCH * HEADS * SEQ * DH;   // 4,194,304 elems
    unsigned short* qh_bf = (unsigned short*)d_ws;         // 8 MB
    unsigned short* kh_bf = qh_bf + TEN;                   // 8 MB
    unsigned short* vt_bf = kh_bf + TEN;                   // 8 MB
    unsigned short* ctxb  = vt_bf + TEN;                   // 8 MB
    unsigned short* Wob   = ctxb + TEN;                    // 2 MB
    u64*            mbits = (u64*)(Wob + EMBED * EMBED);   // 1 MB  (35 MB total)

    proj_mfma<<<dim3(1024, 4), 256, 0, stream>>>(
        q, k, v, Wq, bq, Wk, bk, Wv, bv,
        qh_bf, kh_bf, vt_bf, mask, mbits, Wo, Wob);
    attn_kernel<<<dim3((SEQ / 128) * BATCH * HEADS), 256, 0, stream>>>(
        qh_bf, kh_bf, vt_bf, mbits, ctxb);
    outproj_mfma<<<dim3(EMBED / 64, BATCH * SEQ / 128), 256, 0, stream>>>(
        ctxb, Wob, bo, out);
}